// Round 1
// baseline (1005.401 us; speedup 1.0000x reference)
//
#include <hip/hip_runtime.h>
#include <stdint.h>

typedef unsigned short u16;
typedef __attribute__((ext_vector_type(8))) short bf16x8;
typedef __attribute__((ext_vector_type(4))) float f32x4;

__device__ __forceinline__ float bf2f(u16 u) {
  union { unsigned int i; float f; } v; v.i = ((unsigned int)u) << 16; return v.f;
}
__device__ __forceinline__ u16 f2bf(float f) {
  union { float f; unsigned int i; } v; v.f = f;
  unsigned int x = v.i;
  return (u16)((x + 0x7fffu + ((x >> 16) & 1u)) >> 16);  // RNE
}

__device__ __forceinline__ void async16(const void* g, void* l) {
  __builtin_amdgcn_global_load_lds(
      (const __attribute__((address_space(1))) void*)g,
      (__attribute__((address_space(3))) void*)l, 16, 0, 0);
}

// ---------------------------------------------------------------- casts ----
__global__ __launch_bounds__(256) void cast_f32_to_bf16(
    const float* __restrict__ x, u16* __restrict__ y, long n) {
  long i = ((long)blockIdx.x * blockDim.x + threadIdx.x) * 8;
  long stride = (long)gridDim.x * blockDim.x * 8;
  for (long j = i; j < n; j += stride) {
    float4 a = ((const float4*)(x + j))[0];
    float4 b = ((const float4*)(x + j))[1];
    unsigned int p0 = (unsigned)f2bf(a.x) | ((unsigned)f2bf(a.y) << 16);
    unsigned int p1 = (unsigned)f2bf(a.z) | ((unsigned)f2bf(a.w) << 16);
    unsigned int p2 = (unsigned)f2bf(b.x) | ((unsigned)f2bf(b.y) << 16);
    unsigned int p3 = (unsigned)f2bf(b.z) | ((unsigned)f2bf(b.w) << 16);
    *(uint4*)(y + j) = make_uint4(p0, p1, p2, p3);
  }
}

// WT[m][n*512+c] = W_m[c*512+n]  (transposed bf16 weights, Bt-form GEMMs)
__global__ __launch_bounds__(256) void castWT(
    const float* __restrict__ Wq, const float* __restrict__ Wk,
    const float* __restrict__ Wv, const float* __restrict__ Wo,
    u16* __restrict__ WT) {
  int idx = blockIdx.x * 256 + threadIdx.x;  // n*512 + c
  int m = blockIdx.y;
  const float* src = (m == 0) ? Wq : (m == 1) ? Wk : (m == 2) ? Wv : Wo;
  int nn = idx >> 9;
  int cc = idx & 511;
  WT[(long)m * 262144 + idx] = f2bf(src[cc * 512 + nn]);
}

// ------------------------------------------------------------ gemm (Bt) ----
// C[m,n] = scale * sum_k A[m,k] * B[n,k]  (+ bias[n])
// MODE 0: bf16 row-major C[z*sC + m*N + n]
// MODE 1: bf16 transposed, batches merged in M (2048 rows/batch):
//         C[(m>>11)*(N*2048) + n*2048 + (m&2047)]
// MODE 2: f32 row-major
template <int MODE>
__global__ __launch_bounds__(256) void gemm_bt(
    const u16* __restrict__ A, const u16* __restrict__ B,
    const float* __restrict__ bias, void* __restrict__ Cout,
    int N, int K, long sA, long sB, long sC, float scale) {
  __shared__ u16 As[128 * 32];
  __shared__ u16 Bs[128 * 32];
  const int t = threadIdx.x;
  const int lane = t & 63;
  const int w = t >> 6;
  const long z = blockIdx.z;
  const u16* Ab = A + z * sA;
  const u16* Bb = B + z * sB;
  const long m0 = (long)blockIdx.x * 128;
  const int n0 = blockIdx.y * 128;

  const int rowA = t >> 2;          // 0..63
  const int col8 = (t & 3) * 8;     // 0,8,16,24
  const int wrow = (w >> 1) * 64;
  const int wcol = (w & 1) * 64;
  const int fr = lane & 15;
  const int fk = (lane >> 4) * 8;

  f32x4 acc[4][4] = {};

  for (int kt = 0; kt < K; kt += 32) {
    const u16* ga = Ab + ((long)(m0 + rowA) * K + kt + col8);
    const u16* gb = Bb + ((long)(n0 + rowA) * K + kt + col8);
    async16(ga, (char*)As + w * 1024);
    async16(ga + 64L * K, (char*)As + 4096 + w * 1024);
    async16(gb, (char*)Bs + w * 1024);
    async16(gb + 64L * K, (char*)Bs + 4096 + w * 1024);
    __syncthreads();

    bf16x8 af[4], bf[4];
#pragma unroll
    for (int m = 0; m < 4; ++m)
      af[m] = *(const bf16x8*)(As + (wrow + m * 16 + fr) * 32 + fk);
#pragma unroll
    for (int n = 0; n < 4; ++n)
      bf[n] = *(const bf16x8*)(Bs + (wcol + n * 16 + fr) * 32 + fk);
#pragma unroll
    for (int m = 0; m < 4; ++m)
#pragma unroll
      for (int n = 0; n < 4; ++n)
        acc[m][n] = __builtin_amdgcn_mfma_f32_16x16x32_bf16(af[m], bf[n], acc[m][n], 0, 0, 0);
    __syncthreads();
  }

  const int er = (lane >> 4) * 4;
  const int ec = lane & 15;
#pragma unroll
  for (int m = 0; m < 4; ++m) {
#pragma unroll
    for (int n = 0; n < 4; ++n) {
#pragma unroll
      for (int i = 0; i < 4; ++i) {
        long gm = m0 + wrow + m * 16 + er + i;
        int gc = n0 + wcol + n * 16 + ec;
        float val = acc[m][n][i] * scale;
        if (bias) val += bias[gc];
        if (MODE == 0) {
          u16* Cp = (u16*)Cout + z * sC;
          Cp[gm * (long)N + gc] = f2bf(val);
        } else if (MODE == 1) {
          long b = gm >> 11, rr = gm & 2047;
          ((u16*)Cout)[b * ((long)N * 2048) + (long)gc * 2048 + rr] = f2bf(val);
        } else {
          float* Cp = (float*)Cout + z * sC;
          Cp[gm * (long)N + gc] = val;
        }
      }
    }
  }
}

// ------------------------------------------------------------- softmax ----
// In-place row softmax over 2048 bf16 cols; writes p = exp(s-max)/sum * inv.
__global__ __launch_bounds__(256) void softmax_rows(u16* __restrict__ S, float inv) {
  long row = blockIdx.x;
  u16* p = S + row * 2048;
  int t = threadIdx.x;
  int lane = t & 63, wv = t >> 6;

  uint4 raw = ((const uint4*)p)[t];
  unsigned int wd[4] = {raw.x, raw.y, raw.z, raw.w};
  float v[8];
#pragma unroll
  for (int j = 0; j < 4; ++j) {
    v[2 * j]     = bf2f((u16)(wd[j] & 0xffffu));
    v[2 * j + 1] = bf2f((u16)(wd[j] >> 16));
  }
  float mx = v[0];
#pragma unroll
  for (int j = 1; j < 8; ++j) mx = fmaxf(mx, v[j]);
  for (int off = 32; off; off >>= 1) mx = fmaxf(mx, __shfl_xor(mx, off));
  __shared__ float rmax[4], rsum[4];
  if (lane == 0) rmax[wv] = mx;
  __syncthreads();
  mx = fmaxf(fmaxf(rmax[0], rmax[1]), fmaxf(rmax[2], rmax[3]));

  float e[8], s = 0.f;
#pragma unroll
  for (int j = 0; j < 8; ++j) { e[j] = __expf(v[j] - mx); s += e[j]; }
  for (int off = 32; off; off >>= 1) s += __shfl_xor(s, off);
  if (lane == 0) rsum[wv] = s;
  __syncthreads();
  s = rsum[0] + rsum[1] + rsum[2] + rsum[3];

  float r = inv / s;
  unsigned int o[4];
#pragma unroll
  for (int j = 0; j < 4; ++j)
    o[j] = (unsigned)f2bf(e[2 * j] * r) | ((unsigned)f2bf(e[2 * j + 1] * r) << 16);
  ((uint4*)p)[t] = make_uint4(o[0], o[1], o[2], o[3]);
}

// -------------------------------------------------------------- launch ----
extern "C" void kernel_launch(void* const* d_in, const int* in_sizes, int n_in,
                              void* d_out, int out_size, void* d_ws, size_t ws_size,
                              hipStream_t stream) {
  const float* query = (const float*)d_in[0];
  const float* key_  = (const float*)d_in[1];
  const float* Wq = (const float*)d_in[2];
  const float* bq = (const float*)d_in[3];
  const float* Wk = (const float*)d_in[4];
  const float* bk = (const float*)d_in[5];
  const float* Wv = (const float*)d_in[6];
  const float* bv = (const float*)d_in[7];
  const float* Wo = (const float*)d_in[8];
  const float* bo = (const float*)d_in[9];
  float* out = (float*)d_out;

  const long tokE = 65536L * 512;               // 33,554,432 elems
  const long bstride = 2048L * 512;             // per-batch q/k/v elems

  // workspace layout (bytes):
  //   [0       , 64M)  Qb bf16    (later reused as attn_out bf16)
  //   [64M     ,128M)  Kb bf16
  //   [128M    ,192M)  vT bf16    (per batch [512][2048])
  //   [192M    ,194M)  WT bf16 x4 (transposed weights)
  //   [194M    , ...)  S  bf16    (g batches x 2048 x 2048)
  char* ws = (char*)d_ws;
  u16* Qb = (u16*)(ws);
  u16* Kb = (u16*)(ws + 67108864L);
  u16* vT = (u16*)(ws + 134217728L);
  u16* WT = (u16*)(ws + 201326592L);
  char* Sbase = ws + 203423744L;
  u16* attn = Qb;  // Qb dead after q-projection

  // q, k live in d_out (134 MB) as scratch; overwritten by final out-proj.
  u16* qb = (u16*)d_out;
  u16* kb = (u16*)((char*)d_out + 67108864L);

  long s_avail = (long)ws_size - 203423744L;
  int g = (int)(s_avail / 8388608L);  // 2048*2048*2 bytes per batch
  if (g < 1) g = 1;
  if (g > 32) g = 32;

  // 1. casts
  cast_f32_to_bf16<<<16384, 256, 0, stream>>>(query, Qb, tokE);
  cast_f32_to_bf16<<<16384, 256, 0, stream>>>(key_, Kb, tokE);
  castWT<<<dim3(1024, 4, 1), 256, 0, stream>>>(Wq, Wk, Wv, Wo, WT);

  // 2. projections (M = 65536 merged)
  dim3 gproj(512, 4, 1);
  gemm_bt<0><<<gproj, 256, 0, stream>>>(Qb, WT,            bq, qb, 512, 512, 0, 0, 0, 1.0f);
  gemm_bt<0><<<gproj, 256, 0, stream>>>(Kb, WT + 262144L,  bk, kb, 512, 512, 0, 0, 0, 1.0f);
  gemm_bt<1><<<gproj, 256, 0, stream>>>(Kb, WT + 524288L,  bv, vT, 512, 512, 0, 0, 0, 1.0f);

  // 3. attention, grouped by available workspace
  for (int b0 = 0; b0 < 32; b0 += g) {
    int bc = (32 - b0 < g) ? (32 - b0) : g;
    u16* Sg = (u16*)Sbase;
    dim3 gs(16, 16, bc);
    gemm_bt<0><<<gs, 256, 0, stream>>>(qb + (long)b0 * bstride, kb + (long)b0 * bstride,
                                       nullptr, Sg, 2048, 512,
                                       bstride, bstride, 2048L * 2048, 1.0f / 512.0f);
    softmax_rows<<<bc * 2048, 256, 0, stream>>>(Sg, 1.0f / 2048.0f);
    dim3 gpv(16, 4, bc);
    gemm_bt<0><<<gpv, 256, 0, stream>>>(Sg, vT + (long)b0 * bstride, nullptr,
                                        attn + (long)b0 * bstride, 512, 2048,
                                        2048L * 2048, bstride, bstride, 1.0f);
  }

  // 4. output projection -> d_out fp32
  gemm_bt<2><<<dim3(512, 4, 1), 256, 0, stream>>>(attn, WT + 786432L, bo, out,
                                                  512, 512, 0, 0, 0, 1.0f);
}

// Round 2
// 854.035 us; speedup vs baseline: 1.1772x; 1.1772x over previous
//
#include <hip/hip_runtime.h>
#include <stdint.h>

typedef unsigned short u16;
typedef __attribute__((ext_vector_type(8))) short bf16x8;
typedef __attribute__((ext_vector_type(4))) float f32x4;

__device__ __forceinline__ float bf2f(u16 u) {
  union { unsigned int i; float f; } v; v.i = ((unsigned int)u) << 16; return v.f;
}
__device__ __forceinline__ u16 f2bf(float f) {
  union { float f; unsigned int i; } v; v.f = f;
  unsigned int x = v.i;
  return (u16)((x + 0x7fffu + ((x >> 16) & 1u)) >> 16);  // RNE
}

__device__ __forceinline__ void async16(const void* g, void* l) {
  __builtin_amdgcn_global_load_lds(
      (const __attribute__((address_space(1))) void*)g,
      (__attribute__((address_space(3))) void*)l, 16, 0, 0);
}

// ---------------------------------------------------------------- casts ----
__global__ __launch_bounds__(256) void cast_f32_to_bf16(
    const float* __restrict__ x, u16* __restrict__ y, long n) {
  long i = ((long)blockIdx.x * blockDim.x + threadIdx.x) * 8;
  long stride = (long)gridDim.x * blockDim.x * 8;
  for (long j = i; j < n; j += stride) {
    float4 a = ((const float4*)(x + j))[0];
    float4 b = ((const float4*)(x + j))[1];
    unsigned int p0 = (unsigned)f2bf(a.x) | ((unsigned)f2bf(a.y) << 16);
    unsigned int p1 = (unsigned)f2bf(a.z) | ((unsigned)f2bf(a.w) << 16);
    unsigned int p2 = (unsigned)f2bf(b.x) | ((unsigned)f2bf(b.y) << 16);
    unsigned int p3 = (unsigned)f2bf(b.z) | ((unsigned)f2bf(b.w) << 16);
    *(uint4*)(y + j) = make_uint4(p0, p1, p2, p3);
  }
}

__global__ __launch_bounds__(256) void castWT(
    const float* __restrict__ Wq, const float* __restrict__ Wk,
    const float* __restrict__ Wv, const float* __restrict__ Wo,
    u16* __restrict__ WT) {
  int idx = blockIdx.x * 256 + threadIdx.x;  // n*512 + c
  int m = blockIdx.y;
  const float* src = (m == 0) ? Wq : (m == 1) ? Wk : (m == 2) ? Wv : Wo;
  int nn = idx >> 9;
  int cc = idx & 511;
  WT[(long)m * 262144 + idx] = f2bf(src[cc * 512 + nn]);
}

// --------------------------------------------------- 256x256 8-wave gemm ----
// C[m,n] = scale * sum_k A[m,k]*B[n,k] (+bias[n]); BK=32, LDS ring of 4 slots.
// Slot layout (32 KiB): A [256][32] bf16 (16K) | B [256][32] bf16 (16K).
// Swizzle: within-row byte off ^= ((row>>1)&3)<<4 (rows are 64 B).
// Stage: linear LDS dest (global_load_lds), inverse-swizzled global source.
// Schedule per tile t: 2 phases, each {ds_read | stage -> barrier ->
// lgkmcnt(0) -> setprio(1) -> 16 MFMA -> setprio(0) -> barrier}; counted
// vmcnt(8) once per tile (ring distance 3 tiles); drains 8->4->0 at the end.
#define WAITVM8 asm volatile("s_waitcnt vmcnt(8)" ::: "memory")
#define WAITVM4 asm volatile("s_waitcnt vmcnt(4)" ::: "memory")
#define WAITVM0 asm volatile("s_waitcnt vmcnt(0)" ::: "memory")
#define WAITLGKM asm volatile("s_waitcnt lgkmcnt(0)" ::: "memory")

#define TILE_BODY(T, DOSTAGE, VMWAIT)                                          \
  do {                                                                         \
    char* rb = lds + ((T) & 3) * 32768;                                        \
    bf16x8 bfr[4], afr[4];                                                     \
    _Pragma("unroll") for (int ni = 0; ni < 4; ++ni)                           \
        bfr[ni] = *(const bf16x8*)(rb + boff + ni * 1024);                     \
    _Pragma("unroll") for (int mi = 0; mi < 4; ++mi)                           \
        afr[mi] = *(const bf16x8*)(rb + aoff + mi * 1024);                     \
    if (DOSTAGE) {                                                             \
      char* sb = lds + (((T) + 3) & 3) * 32768 + ldsW;                         \
      async16(pa, sb);                                                         \
      async16(pa + 128 * (long)K, sb + 8192);                                  \
    }                                                                          \
    __builtin_amdgcn_s_barrier();                                              \
    WAITLGKM;                                                                  \
    __builtin_amdgcn_sched_barrier(0);                                         \
    __builtin_amdgcn_s_setprio(1);                                             \
    _Pragma("unroll") for (int mi = 0; mi < 4; ++mi)                           \
        _Pragma("unroll") for (int ni = 0; ni < 4; ++ni)                       \
            acc[mi][ni] = __builtin_amdgcn_mfma_f32_16x16x32_bf16(             \
                afr[mi], bfr[ni], acc[mi][ni], 0, 0, 0);                       \
    __builtin_amdgcn_s_setprio(0);                                             \
    __builtin_amdgcn_s_barrier();                                              \
    _Pragma("unroll") for (int mi = 0; mi < 4; ++mi)                           \
        afr[mi] = *(const bf16x8*)(rb + aoff + (mi + 4) * 1024);               \
    if (DOSTAGE) {                                                             \
      char* sb = lds + (((T) + 3) & 3) * 32768 + 16384 + ldsW;                 \
      async16(pb, sb);                                                         \
      async16(pb + 128 * (long)K, sb + 8192);                                  \
      pa += 32; pb += 32;                                                      \
    }                                                                          \
    __builtin_amdgcn_s_barrier();                                              \
    WAITLGKM;                                                                  \
    __builtin_amdgcn_sched_barrier(0);                                         \
    __builtin_amdgcn_s_setprio(1);                                             \
    _Pragma("unroll") for (int mi = 0; mi < 4; ++mi)                           \
        _Pragma("unroll") for (int ni = 0; ni < 4; ++ni)                       \
            acc[mi + 4][ni] = __builtin_amdgcn_mfma_f32_16x16x32_bf16(         \
                afr[mi], bfr[ni], acc[mi + 4][ni], 0, 0, 0);                   \
    __builtin_amdgcn_s_setprio(0);                                             \
    VMWAIT;                                                                    \
    __builtin_amdgcn_s_barrier();                                              \
  } while (0)

template <int MODE>
__global__ __launch_bounds__(512, 2) void gemm256(
    const u16* __restrict__ A, const u16* __restrict__ B,
    const float* __restrict__ bias, void* __restrict__ Cout,
    int N, int K, long sA, long sB, long sC, float scale) {
  __shared__ __align__(16) char lds[4 * 32768];
  const int t = threadIdx.x;
  const int lane = t & 63;
  const int w = t >> 6;        // 0..7
  const int wm = w >> 2;       // 0..1
  const int wn = w & 3;        // 0..3
  const long z = blockIdx.z;
  const long m0 = (long)blockIdx.x * 256;
  const int n0 = blockIdx.y * 256;
  const int nt = K >> 5;       // BK=32 tiles (all call sites: nt >= 16)

  // ---- staging geometry (linear LDS dest, inverse-swizzled global src) ----
  const int srow = w * 16 + (lane >> 2);                      // 0..127
  const int koff = 8 * ((lane & 3) ^ ((lane >> 3) & 3));      // elems
  const int ldsW = w * 1024;
  const u16* pa = A + z * sA + (m0 + srow) * (long)K + koff;
  const u16* pb = B + z * sB + ((long)(n0 + srow)) * K + koff;

  // ---- read geometry (swizzled ds_read_b128) ----
  const int frow = lane & 15;
  const int kb = (lane >> 4) * 16;                            // bytes
  const int sw = ((frow >> 1) & 3) << 4;
  const int aoff = (wm * 128 + frow) * 64 + (kb ^ sw);
  const int boff = 16384 + (wn * 64 + frow) * 64 + (kb ^ sw);

  f32x4 acc[8][4] = {};

  // ---- prologue: stage tiles 0,1,2 into slots 0,1,2 ----
#pragma unroll
  for (int pt = 0; pt < 3; ++pt) {
    char* sb = lds + pt * 32768 + ldsW;
    async16(pa, sb);
    async16(pa + 128 * (long)K, sb + 8192);
    async16(pb, sb + 16384);
    async16(pb + 128 * (long)K, sb + 24576);
    pa += 32;
    pb += 32;
  }
  WAITVM8;  // tile 0 fully landed
  __builtin_amdgcn_s_barrier();

  // ---- main loop ----
  for (int tt = 0; tt < nt - 3; ++tt) TILE_BODY(tt, true, WAITVM8);
  TILE_BODY(nt - 3, false, WAITVM4);
  TILE_BODY(nt - 2, false, WAITVM0);
  TILE_BODY(nt - 1, false, (void)0);

  // ---- epilogue ----
  const int er = (lane >> 4) * 4;
  const int ec = lane & 15;
#pragma unroll
  for (int mi = 0; mi < 8; ++mi) {
#pragma unroll
    for (int ni = 0; ni < 4; ++ni) {
#pragma unroll
      for (int i = 0; i < 4; ++i) {
        long gm = m0 + wm * 128 + mi * 16 + er + i;
        int gc = n0 + wn * 64 + ni * 16 + ec;
        float val = acc[mi][ni][i] * scale;
        if (bias) val += bias[gc];
        if (MODE == 0) {
          ((u16*)Cout + z * sC)[gm * (long)N + gc] = f2bf(val);
        } else if (MODE == 1) {
          long b = gm >> 11, rr = gm & 2047;
          ((u16*)Cout)[b * ((long)N * 2048) + (long)gc * 2048 + rr] = f2bf(val);
        } else {
          ((float*)Cout + z * sC)[gm * (long)N + gc] = val;
        }
      }
    }
  }
}

// ------------------------------------------------------------- softmax ----
__global__ __launch_bounds__(256) void softmax_rows(u16* __restrict__ S, float inv) {
  long row = blockIdx.x;
  u16* p = S + row * 2048;
  int t = threadIdx.x;
  int lane = t & 63, wv = t >> 6;

  uint4 raw = ((const uint4*)p)[t];
  unsigned int wd[4] = {raw.x, raw.y, raw.z, raw.w};
  float v[8];
#pragma unroll
  for (int j = 0; j < 4; ++j) {
    v[2 * j]     = bf2f((u16)(wd[j] & 0xffffu));
    v[2 * j + 1] = bf2f((u16)(wd[j] >> 16));
  }
  float mx = v[0];
#pragma unroll
  for (int j = 1; j < 8; ++j) mx = fmaxf(mx, v[j]);
  for (int off = 32; off; off >>= 1) mx = fmaxf(mx, __shfl_xor(mx, off));
  __shared__ float rmax[4], rsum[4];
  if (lane == 0) rmax[wv] = mx;
  __syncthreads();
  mx = fmaxf(fmaxf(rmax[0], rmax[1]), fmaxf(rmax[2], rmax[3]));

  float e[8], s = 0.f;
#pragma unroll
  for (int j = 0; j < 8; ++j) { e[j] = __expf(v[j] - mx); s += e[j]; }
  for (int off = 32; off; off >>= 1) s += __shfl_xor(s, off);
  if (lane == 0) rsum[wv] = s;
  __syncthreads();
  s = rsum[0] + rsum[1] + rsum[2] + rsum[3];

  float r = inv / s;
  unsigned int o[4];
#pragma unroll
  for (int j = 0; j < 4; ++j)
    o[j] = (unsigned)f2bf(e[2 * j] * r) | ((unsigned)f2bf(e[2 * j + 1] * r) << 16);
  ((uint4*)p)[t] = make_uint4(o[0], o[1], o[2], o[3]);
}

// -------------------------------------------------------------- launch ----
extern "C" void kernel_launch(void* const* d_in, const int* in_sizes, int n_in,
                              void* d_out, int out_size, void* d_ws, size_t ws_size,
                              hipStream_t stream) {
  const float* query = (const float*)d_in[0];
  const float* key_  = (const float*)d_in[1];
  const float* Wq = (const float*)d_in[2];
  const float* bq = (const float*)d_in[3];
  const float* Wk = (const float*)d_in[4];
  const float* bk = (const float*)d_in[5];
  const float* Wv = (const float*)d_in[6];
  const float* bv = (const float*)d_in[7];
  const float* Wo = (const float*)d_in[8];
  const float* bo = (const float*)d_in[9];
  float* out = (float*)d_out;

  const long tokE = 65536L * 512;
  const long bstride = 2048L * 512;

  char* ws = (char*)d_ws;
  u16* Qb = (u16*)(ws);
  u16* Kb = (u16*)(ws + 67108864L);
  u16* vT = (u16*)(ws + 134217728L);
  u16* WT = (u16*)(ws + 201326592L);
  char* Sbase = ws + 203423744L;
  u16* attn = Qb;  // Qb dead after q-projection

  u16* qb = (u16*)d_out;
  u16* kb = (u16*)((char*)d_out + 67108864L);

  long s_avail = (long)ws_size - 203423744L;
  int g = (int)(s_avail / 8388608L);
  if (g < 1) g = 1;
  if (g > 32) g = 32;

  // 1. casts
  cast_f32_to_bf16<<<16384, 256, 0, stream>>>(query, Qb, tokE);
  cast_f32_to_bf16<<<16384, 256, 0, stream>>>(key_, Kb, tokE);
  castWT<<<dim3(1024, 4, 1), 256, 0, stream>>>(Wq, Wk, Wv, Wo, WT);

  // 2. projections (M = 65536 merged)
  dim3 gproj(256, 2, 1);
  gemm256<0><<<gproj, 512, 0, stream>>>(Qb, WT,           bq, qb, 512, 512, 0, 0, 0, 1.0f);
  gemm256<0><<<gproj, 512, 0, stream>>>(Kb, WT + 262144L, bk, kb, 512, 512, 0, 0, 0, 1.0f);
  gemm256<1><<<gproj, 512, 0, stream>>>(Kb, WT + 524288L, bv, vT, 512, 512, 0, 0, 0, 1.0f);

  // 3. attention, grouped by available workspace
  for (int b0 = 0; b0 < 32; b0 += g) {
    int bc = (32 - b0 < g) ? (32 - b0) : g;
    u16* Sg = (u16*)Sbase;
    dim3 gs(8, 8, bc);
    gemm256<0><<<gs, 512, 0, stream>>>(qb + (long)b0 * bstride, kb + (long)b0 * bstride,
                                       nullptr, Sg, 2048, 512,
                                       bstride, bstride, 2048L * 2048, 1.0f / 512.0f);
    softmax_rows<<<bc * 2048, 256, 0, stream>>>(Sg, 1.0f / 2048.0f);
    dim3 gpv(8, 2, bc);
    gemm256<0><<<gpv, 512, 0, stream>>>(Sg, vT + (long)b0 * bstride, nullptr,
                                        attn + (long)b0 * bstride, 512, 2048,
                                        2048L * 2048, bstride, bstride, 1.0f);
  }

  // 4. output projection -> d_out fp32
  gemm256<2><<<dim3(256, 2, 1), 512, 0, stream>>>(attn, WT + 786432L, bo, out,
                                                  512, 512, 0, 0, 0, 1.0f);
}

// Round 3
// 803.429 us; speedup vs baseline: 1.2514x; 1.0630x over previous
//
#include <hip/hip_runtime.h>
#include <stdint.h>

typedef unsigned short u16;
typedef __attribute__((ext_vector_type(8))) short bf16x8;
typedef __attribute__((ext_vector_type(4))) float f32x4;

__device__ __forceinline__ float bf2f(u16 u) {
  union { unsigned int i; float f; } v; v.i = ((unsigned int)u) << 16; return v.f;
}
__device__ __forceinline__ u16 f2bf(float f) {
  union { float f; unsigned int i; } v; v.f = f;
  unsigned int x = v.i;
  return (u16)((x + 0x7fffu + ((x >> 16) & 1u)) >> 16);  // RNE
}

__device__ __forceinline__ void async16(const void* g, void* l) {
  __builtin_amdgcn_global_load_lds(
      (const __attribute__((address_space(1))) void*)g,
      (__attribute__((address_space(3))) void*)l, 16, 0, 0);
}

// ---------------------------------------------------------------- casts ----
__global__ __launch_bounds__(256) void cast_f32_to_bf16(
    const float* __restrict__ x, u16* __restrict__ y, long n) {
  long i = ((long)blockIdx.x * blockDim.x + threadIdx.x) * 8;
  long stride = (long)gridDim.x * blockDim.x * 8;
  for (long j = i; j < n; j += stride) {
    float4 a = ((const float4*)(x + j))[0];
    float4 b = ((const float4*)(x + j))[1];
    unsigned int p0 = (unsigned)f2bf(a.x) | ((unsigned)f2bf(a.y) << 16);
    unsigned int p1 = (unsigned)f2bf(a.z) | ((unsigned)f2bf(a.w) << 16);
    unsigned int p2 = (unsigned)f2bf(b.x) | ((unsigned)f2bf(b.y) << 16);
    unsigned int p3 = (unsigned)f2bf(b.z) | ((unsigned)f2bf(b.w) << 16);
    *(uint4*)(y + j) = make_uint4(p0, p1, p2, p3);
  }
}

__global__ __launch_bounds__(256) void castWT(
    const float* __restrict__ Wq, const float* __restrict__ Wk,
    const float* __restrict__ Wv, const float* __restrict__ Wo,
    u16* __restrict__ WT) {
  int idx = blockIdx.x * 256 + threadIdx.x;  // n*512 + c
  int m = blockIdx.y;
  const float* src = (m == 0) ? Wq : (m == 1) ? Wk : (m == 2) ? Wv : Wo;
  int nn = idx >> 9;
  int cc = idx & 511;
  WT[(long)m * 262144 + idx] = f2bf(src[cc * 512 + nn]);
}

// --------------------------------------------------- 256x256 8-wave gemm ----
// C[m,n] = scale * sum_k A[m,k]*B[n,k] (+bias[n]); BK=32, LDS ring of 4 slots.
// Slot (32 KiB): A [256][32] bf16 | B [256][32] bf16. Read swizzle:
// byte ^= ((row>>1)&3)<<4; stage = linear LDS dest + inverse-swizzled src.
// Schedule: 2 phases/tile, raw s_barrier pairs around each 16-MFMA cluster,
// counted vmcnt(8) once per tile (ring distance 3). NO manual lgkmcnt /
// sched_barrier — compiler's fine-grained lgkmcnt gives MFMA/LDS overlap.
#define WAITVM8 asm volatile("s_waitcnt vmcnt(8)" ::: "memory")
#define WAITVM4 asm volatile("s_waitcnt vmcnt(4)" ::: "memory")
#define WAITVM0 asm volatile("s_waitcnt vmcnt(0)" ::: "memory")

#define TILE_BODY(T, DOSTAGE, VMWAIT)                                          \
  do {                                                                         \
    char* rb = lds + ((T) & 3) * 32768;                                        \
    bf16x8 bfr[4], afr[4];                                                     \
    _Pragma("unroll") for (int ni = 0; ni < 4; ++ni)                           \
        bfr[ni] = *(const bf16x8*)(rb + boff + ni * 1024);                     \
    _Pragma("unroll") for (int mi = 0; mi < 4; ++mi)                           \
        afr[mi] = *(const bf16x8*)(rb + aoff + mi * 1024);                     \
    if (DOSTAGE) {                                                             \
      char* sb = lds + (((T) + 3) & 3) * 32768 + ldsW;                         \
      async16(pa, sb);                                                         \
      async16(pa + 128 * (long)K, sb + 8192);                                  \
    }                                                                          \
    __builtin_amdgcn_s_barrier();                                              \
    __builtin_amdgcn_s_setprio(1);                                             \
    _Pragma("unroll") for (int mi = 0; mi < 4; ++mi)                           \
        _Pragma("unroll") for (int ni = 0; ni < 4; ++ni)                       \
            acc[mi][ni] = __builtin_amdgcn_mfma_f32_16x16x32_bf16(             \
                afr[mi], bfr[ni], acc[mi][ni], 0, 0, 0);                       \
    __builtin_amdgcn_s_setprio(0);                                             \
    __builtin_amdgcn_s_barrier();                                              \
    _Pragma("unroll") for (int mi = 0; mi < 4; ++mi)                           \
        afr[mi] = *(const bf16x8*)(rb + aoff + (mi + 4) * 1024);               \
    if (DOSTAGE) {                                                             \
      char* sb = lds + (((T) + 3) & 3) * 32768 + 16384 + ldsW;                 \
      async16(pb, sb);                                                         \
      async16(pb + 128 * (long)K, sb + 8192);                                  \
      pa += 32; pb += 32;                                                      \
    }                                                                          \
    __builtin_amdgcn_s_barrier();                                              \
    __builtin_amdgcn_s_setprio(1);                                             \
    _Pragma("unroll") for (int mi = 0; mi < 4; ++mi)                           \
        _Pragma("unroll") for (int ni = 0; ni < 4; ++ni)                       \
            acc[mi + 4][ni] = __builtin_amdgcn_mfma_f32_16x16x32_bf16(         \
                afr[mi], bfr[ni], acc[mi + 4][ni], 0, 0, 0);                   \
    __builtin_amdgcn_s_setprio(0);                                             \
    VMWAIT;                                                                    \
    __builtin_amdgcn_s_barrier();                                              \
  } while (0)

template <int MODE>
__global__ __launch_bounds__(512, 2) void gemm256(
    const u16* __restrict__ A, const u16* __restrict__ B,
    const float* __restrict__ bias, void* __restrict__ Cout,
    int N, int K, long sA, long sB, long sC, float scale) {
  __shared__ __align__(16) char lds[4 * 32768];
  const int t = threadIdx.x;
  const int lane = t & 63;
  const int w = t >> 6;        // 0..7
  const int wm = w >> 2;       // 0..1
  const int wn = w & 3;        // 0..3
  const long z = blockIdx.z;
  const long m0 = (long)blockIdx.x * 256;
  const int n0 = blockIdx.y * 256;
  const int nt = K >> 5;       // BK=32 tiles (all call sites: nt >= 16)

  // ---- staging geometry (linear LDS dest, inverse-swizzled global src) ----
  const int srow = w * 16 + (lane >> 2);                      // 0..127
  const int koff = 8 * ((lane & 3) ^ ((lane >> 3) & 3));      // elems
  const int ldsW = w * 1024;
  const u16* pa = A + z * sA + (m0 + srow) * (long)K + koff;
  const u16* pb = B + z * sB + ((long)(n0 + srow)) * K + koff;

  // ---- read geometry (swizzled ds_read_b128) ----
  const int frow = lane & 15;
  const int kb = (lane >> 4) * 16;                            // bytes
  const int sw = ((frow >> 1) & 3) << 4;
  const int aoff = (wm * 128 + frow) * 64 + (kb ^ sw);
  const int boff = 16384 + (wn * 64 + frow) * 64 + (kb ^ sw);

  f32x4 acc[8][4] = {};

  // ---- prologue: stage tiles 0,1,2 into slots 0,1,2 ----
#pragma unroll
  for (int pt = 0; pt < 3; ++pt) {
    char* sb = lds + pt * 32768 + ldsW;
    async16(pa, sb);
    async16(pa + 128 * (long)K, sb + 8192);
    async16(pb, sb + 16384);
    async16(pb + 128 * (long)K, sb + 24576);
    pa += 32;
    pb += 32;
  }
  WAITVM8;  // tile 0 fully landed
  __builtin_amdgcn_s_barrier();

  // ---- main loop ----
  for (int tt = 0; tt < nt - 3; ++tt) TILE_BODY(tt, true, WAITVM8);
  TILE_BODY(nt - 3, false, WAITVM4);
  TILE_BODY(nt - 2, false, WAITVM0);
  TILE_BODY(nt - 1, false, (void)0);

  // ---- epilogue ----
  const int er = (lane >> 4) * 4;
  const int ec = lane & 15;
  if (MODE == 0) {
    // LDS-transposed coalesced store: 2 passes x 128 rows, stride 264 u16.
    u16* Ep = (u16*)lds;
    u16* Cp = (u16*)Cout + z * sC;
    float bv[4];
#pragma unroll
    for (int ni = 0; ni < 4; ++ni)
      bv[ni] = bias ? bias[n0 + wn * 64 + ni * 16 + ec] : 0.0f;
#pragma unroll
    for (int p = 0; p < 2; ++p) {
      __syncthreads();
#pragma unroll
      for (int m2 = 0; m2 < 4; ++m2) {
#pragma unroll
        for (int ni = 0; ni < 4; ++ni) {
#pragma unroll
          for (int i = 0; i < 4; ++i) {
            float val = acc[p * 4 + m2][ni][i] * scale + bv[ni];
            Ep[(wm * 64 + m2 * 16 + er + i) * 264 + wn * 64 + ni * 16 + ec] =
                f2bf(val);
          }
        }
      }
      __syncthreads();
#pragma unroll
      for (int s = 0; s < 8; ++s) {
        int R = w * 2 + (lane >> 5) + s * 16;
        int j = lane & 31;
        uint4 d = *(const uint4*)(Ep + R * 264 + j * 8);
        long gm = m0 + (R >> 6) * 128 + p * 64 + (R & 63);
        *(uint4*)(Cp + gm * (long)N + n0 + j * 8) = d;
      }
    }
  } else {
#pragma unroll
    for (int mi = 0; mi < 8; ++mi) {
#pragma unroll
      for (int ni = 0; ni < 4; ++ni) {
#pragma unroll
        for (int i = 0; i < 4; ++i) {
          long gm = m0 + wm * 128 + mi * 16 + er + i;
          int gc = n0 + wn * 64 + ni * 16 + ec;
          float val = acc[mi][ni][i] * scale;
          if (bias) val += bias[gc];
          if (MODE == 1) {
            long b = gm >> 11, rr = gm & 2047;
            ((u16*)Cout)[b * ((long)N * 2048) + (long)gc * 2048 + rr] = f2bf(val);
          } else {
            ((float*)Cout + z * sC)[gm * (long)N + gc] = val;
          }
        }
      }
    }
  }
}

// ------------------------------------------------------------- softmax ----
__global__ __launch_bounds__(256) void softmax_rows(u16* __restrict__ S, float inv) {
  long row = blockIdx.x;
  u16* p = S + row * 2048;
  int t = threadIdx.x;
  int lane = t & 63, wv = t >> 6;

  uint4 raw = ((const uint4*)p)[t];
  unsigned int wd[4] = {raw.x, raw.y, raw.z, raw.w};
  float v[8];
#pragma unroll
  for (int j = 0; j < 4; ++j) {
    v[2 * j]     = bf2f((u16)(wd[j] & 0xffffu));
    v[2 * j + 1] = bf2f((u16)(wd[j] >> 16));
  }
  float mx = v[0];
#pragma unroll
  for (int j = 1; j < 8; ++j) mx = fmaxf(mx, v[j]);
  for (int off = 32; off; off >>= 1) mx = fmaxf(mx, __shfl_xor(mx, off));
  __shared__ float rmax[4], rsum[4];
  if (lane == 0) rmax[wv] = mx;
  __syncthreads();
  mx = fmaxf(fmaxf(rmax[0], rmax[1]), fmaxf(rmax[2], rmax[3]));

  float e[8], s = 0.f;
#pragma unroll
  for (int j = 0; j < 8; ++j) { e[j] = __expf(v[j] - mx); s += e[j]; }
  for (int off = 32; off; off >>= 1) s += __shfl_xor(s, off);
  if (lane == 0) rsum[wv] = s;
  __syncthreads();
  s = rsum[0] + rsum[1] + rsum[2] + rsum[3];

  float r = inv / s;
  unsigned int o[4];
#pragma unroll
  for (int j = 0; j < 4; ++j)
    o[j] = (unsigned)f2bf(e[2 * j] * r) | ((unsigned)f2bf(e[2 * j + 1] * r) << 16);
  ((uint4*)p)[t] = make_uint4(o[0], o[1], o[2], o[3]);
}

// -------------------------------------------------------------- launch ----
extern "C" void kernel_launch(void* const* d_in, const int* in_sizes, int n_in,
                              void* d_out, int out_size, void* d_ws, size_t ws_size,
                              hipStream_t stream) {
  const float* query = (const float*)d_in[0];
  const float* key_  = (const float*)d_in[1];
  const float* Wq = (const float*)d_in[2];
  const float* bq = (const float*)d_in[3];
  const float* Wk = (const float*)d_in[4];
  const float* bk = (const float*)d_in[5];
  const float* Wv = (const float*)d_in[6];
  const float* bv = (const float*)d_in[7];
  const float* Wo = (const float*)d_in[8];
  const float* bo = (const float*)d_in[9];
  float* out = (float*)d_out;

  const long tokE = 65536L * 512;
  const long bstride = 2048L * 512;

  char* ws = (char*)d_ws;
  u16* Qb = (u16*)(ws);
  u16* Kb = (u16*)(ws + 67108864L);
  u16* vT = (u16*)(ws + 134217728L);
  u16* WT = (u16*)(ws + 201326592L);
  char* Sbase = ws + 203423744L;
  u16* attn = Qb;  // Qb dead after q-projection

  u16* qb = (u16*)d_out;
  u16* kb = (u16*)((char*)d_out + 67108864L);

  long s_avail = (long)ws_size - 203423744L;
  int g = (int)(s_avail / 8388608L);
  if (g < 1) g = 1;
  if (g > 32) g = 32;

  // 1. casts
  cast_f32_to_bf16<<<16384, 256, 0, stream>>>(query, Qb, tokE);
  cast_f32_to_bf16<<<16384, 256, 0, stream>>>(key_, Kb, tokE);
  castWT<<<dim3(1024, 4, 1), 256, 0, stream>>>(Wq, Wk, Wv, Wo, WT);

  // 2. projections (M = 65536 merged)
  dim3 gproj(256, 2, 1);
  gemm256<0><<<gproj, 512, 0, stream>>>(Qb, WT,           bq, qb, 512, 512, 0, 0, 0, 1.0f);
  gemm256<0><<<gproj, 512, 0, stream>>>(Kb, WT + 262144L, bk, kb, 512, 512, 0, 0, 0, 1.0f);
  gemm256<1><<<gproj, 512, 0, stream>>>(Kb, WT + 524288L, bv, vT, 512, 512, 0, 0, 0, 1.0f);

  // 3. attention, grouped by available workspace
  for (int b0 = 0; b0 < 32; b0 += g) {
    int bc = (32 - b0 < g) ? (32 - b0) : g;
    u16* Sg = (u16*)Sbase;
    dim3 gs(8, 8, bc);
    gemm256<0><<<gs, 512, 0, stream>>>(qb + (long)b0 * bstride, kb + (long)b0 * bstride,
                                       nullptr, Sg, 2048, 512,
                                       bstride, bstride, 2048L * 2048, 1.0f / 512.0f);
    softmax_rows<<<bc * 2048, 256, 0, stream>>>(Sg, 1.0f / 2048.0f);
    dim3 gpv(8, 2, bc);
    gemm256<0><<<gpv, 512, 0, stream>>>(Sg, vT + (long)b0 * bstride, nullptr,
                                        attn + (long)b0 * bstride, 512, 2048,
                                        2048L * 2048, bstride, bstride, 1.0f);
  }

  // 4. output projection -> d_out fp32
  gemm256<2><<<dim3(256, 2, 1), 512, 0, stream>>>(attn, WT + 786432L, bo, out,
                                                  512, 512, 0, 0, 0, 1.0f);
}

// Round 4
// 799.015 us; speedup vs baseline: 1.2583x; 1.0055x over previous
//
#include <hip/hip_runtime.h>
#include <stdint.h>

typedef unsigned short u16;
typedef __attribute__((ext_vector_type(8))) short bf16x8;
typedef __attribute__((ext_vector_type(4))) float f32x4;

__device__ __forceinline__ float bf2f(u16 u) {
  union { unsigned int i; float f; } v; v.i = ((unsigned int)u) << 16; return v.f;
}
__device__ __forceinline__ u16 f2bf(float f) {
  union { float f; unsigned int i; } v; v.f = f;
  unsigned int x = v.i;
  return (u16)((x + 0x7fffu + ((x >> 16) & 1u)) >> 16);  // RNE
}

__device__ __forceinline__ void async16(const void* g, void* l) {
  __builtin_amdgcn_global_load_lds(
      (const __attribute__((address_space(1))) void*)g,
      (__attribute__((address_space(3))) void*)l, 16, 0, 0);
}

// ---------------------------------------------------------------- casts ----
__global__ __launch_bounds__(256) void cast_f32_to_bf16(
    const float* __restrict__ x, u16* __restrict__ y, long n) {
  long i = ((long)blockIdx.x * blockDim.x + threadIdx.x) * 8;
  long stride = (long)gridDim.x * blockDim.x * 8;
  for (long j = i; j < n; j += stride) {
    float4 a = ((const float4*)(x + j))[0];
    float4 b = ((const float4*)(x + j))[1];
    unsigned int p0 = (unsigned)f2bf(a.x) | ((unsigned)f2bf(a.y) << 16);
    unsigned int p1 = (unsigned)f2bf(a.z) | ((unsigned)f2bf(a.w) << 16);
    unsigned int p2 = (unsigned)f2bf(b.x) | ((unsigned)f2bf(b.y) << 16);
    unsigned int p3 = (unsigned)f2bf(b.z) | ((unsigned)f2bf(b.w) << 16);
    *(uint4*)(y + j) = make_uint4(p0, p1, p2, p3);
  }
}

__global__ __launch_bounds__(256) void castWT(
    const float* __restrict__ Wq, const float* __restrict__ Wk,
    const float* __restrict__ Wv, const float* __restrict__ Wo,
    u16* __restrict__ WT) {
  int idx = blockIdx.x * 256 + threadIdx.x;  // n*512 + c
  int m = blockIdx.y;
  const float* src = (m == 0) ? Wq : (m == 1) ? Wk : (m == 2) ? Wv : Wo;
  int nn = idx >> 9;
  int cc = idx & 511;
  WT[(long)m * 262144 + idx] = f2bf(src[cc * 512 + nn]);
}

// --------------------------------------------------- 256x256 8-wave gemm ----
// C[m,n] = scale * sum_k A[m,k]*B[n,k] (+bias[n]); BK=32, LDS ring of 4 slots.
// Slot (32 KiB): A [256][32] bf16 | B [256][32] bf16. Read swizzle:
// byte ^= ((row>>1)&3)<<4; stage = linear LDS dest + inverse-swizzled src.
//
// Pipeline (one-phase-ahead reads, counted waits; nt MUST be even):
//   phase (T,0): stage A(T+3); vmcnt(6); BAR; asm-read A(1,T)->A1 (4);
//                lgkmcnt(4)+sched_barrier; MFMA mh0 (A0 x Bcur); BAR
//   phase (T,1): stage B(T+3); vmcnt(6); BAR; asm-read A(0,T+1)->A0,
//                B(:,T+1)->Bnext (8); lgkmcnt(8)+sched_barrier;
//                MFMA mh1 (A1 x Bcur); BAR
// vmcnt ledger (2 stage-loads/phase): steady vmcnt(6) drains the stage from
// 3 phases back = tile T+3 fully landed before its first read at (T+2,1).
// Tail (no staging): vmcnt 4 -> 2 -> 0 at (nt-3,0),(nt-3,1),(nt-2,0).
// WAR: slot of tile T-1 is re-staged at (T,0); its last reads returned by
// (T-1,1)'s lgkm (pre-MFMA), ordered by the (T-1,1) end-barrier. Safe.

#define DSR4(d, adr)                                                   \
  asm volatile("ds_read_b128 %0, %4 offset:0\n\t"                     \
               "ds_read_b128 %1, %4 offset:1024\n\t"                   \
               "ds_read_b128 %2, %4 offset:2048\n\t"                   \
               "ds_read_b128 %3, %4 offset:3072"                       \
               : "=&v"(d[0]), "=&v"(d[1]), "=&v"(d[2]), "=&v"(d[3])    \
               : "v"(adr))

#define LGKM(n)                                      \
  asm volatile("s_waitcnt lgkmcnt(" #n ")");         \
  __builtin_amdgcn_sched_barrier(0)
#define VMC(n) asm volatile("s_waitcnt vmcnt(" #n ")" ::: "memory")
#define BAR() __builtin_amdgcn_s_barrier()

#define MFMA16(mh, Aset, Bset)                                               \
  __builtin_amdgcn_s_setprio(1);                                             \
  _Pragma("unroll") for (int mi = 0; mi < 4; ++mi)                           \
  _Pragma("unroll") for (int ni = 0; ni < 4; ++ni)                           \
      acc[(mh)*4 + mi][ni] = __builtin_amdgcn_mfma_f32_16x16x32_bf16(        \
          Aset[mi], Bset[ni], acc[(mh)*4 + mi][ni], 0, 0, 0);                \
  __builtin_amdgcn_s_setprio(0)

// VMSTMT: pass VMC(n) or (void)0
#define PH0(T, Bcur, DOSTAGE, VMSTMT)                                  \
  do {                                                                 \
    if (DOSTAGE) {                                                     \
      char* sb = lds + (((T) + 3) & 3) * 32768 + ldsW;                 \
      async16(pa, sb);                                                 \
      async16(pa + 128 * (long)K, sb + 8192);                          \
      pa += 32;                                                        \
    }                                                                  \
    VMSTMT;                                                            \
    BAR();                                                             \
    { unsigned adr = ldsb + ((T)&3) * 32768 + aoff1r; DSR4(A1, adr); } \
    LGKM(4);                                                           \
    MFMA16(0, A0, Bcur);                                               \
    BAR();                                                             \
  } while (0)

#define PH1(T, Bcur, Bnext, DOSTAGE, VMSTMT, DOREAD)                     \
  do {                                                                   \
    if (DOSTAGE) {                                                       \
      char* sb = lds + (((T) + 3) & 3) * 32768 + 16384 + ldsW;           \
      async16(pb, sb);                                                   \
      async16(pb + 128 * (long)K, sb + 8192);                            \
      pb += 32;                                                          \
    }                                                                    \
    VMSTMT;                                                              \
    BAR();                                                               \
    if (DOREAD) {                                                        \
      unsigned s1 = ldsb + (((T) + 1) & 3) * 32768;                      \
      DSR4(A0, s1 + aoff0r);                                             \
      DSR4(Bnext, s1 + boffr);                                           \
      LGKM(8);                                                           \
    } else {                                                             \
      LGKM(0);                                                           \
    }                                                                    \
    MFMA16(1, A1, Bcur);                                                 \
    BAR();                                                               \
  } while (0)

template <int MODE>
__global__ __launch_bounds__(512, 2) void gemm256(
    const u16* __restrict__ A, const u16* __restrict__ B,
    const float* __restrict__ bias, void* __restrict__ Cout,
    int N, int K, long sA, long sB, long sC, float scale) {
  __shared__ __align__(16) char lds[4 * 32768];
  const int t = threadIdx.x;
  const int lane = t & 63;
  const int w = t >> 6;        // 0..7
  const int wm = w >> 2;       // 0..1
  const int wn = w & 3;        // 0..3
  const long z = blockIdx.z;
  const long m0 = (long)blockIdx.x * 256;
  const int n0 = blockIdx.y * 256;
  const int nt = K >> 5;       // BK=32 tiles; all call sites: nt even, >= 8

  // ---- staging geometry (linear LDS dest, inverse-swizzled global src) ----
  const int srow = w * 16 + (lane >> 2);                      // 0..127
  const int koff = 8 * ((lane & 3) ^ ((lane >> 3) & 3));      // elems
  const int ldsW = w * 1024;
  const u16* pa = A + z * sA + (m0 + srow) * (long)K + koff;
  const u16* pb = B + z * sB + ((long)(n0 + srow)) * K + koff;

  // ---- read geometry (swizzled ds_read_b128, asm) ----
  const int fr = lane & 15;
  const int kb = (lane >> 4) * 16;                            // bytes
  const int sw = ((fr >> 1) & 3) << 4;
  const unsigned ldsb =
      (unsigned)(uintptr_t)(__attribute__((address_space(3))) char*)lds;
  const unsigned aoff0r = (unsigned)((wm * 128 + fr) * 64 + (kb ^ sw));
  const unsigned aoff1r = aoff0r + 4096;  // +64 rows
  const unsigned boffr = (unsigned)(16384 + (wn * 64 + fr) * 64 + (kb ^ sw));

  bf16x8 A0[4], A1[4], B0[4], B1[4];
  f32x4 acc[8][4] = {};

  // ---- prologue: stage tiles 0,1,2 into slots 0,1,2 (A0,A1,B0,B1 each) ----
#pragma unroll
  for (int pt = 0; pt < 3; ++pt) {
    char* sb = lds + pt * 32768 + ldsW;
    async16(pa, sb);
    async16(pa + 128 * (long)K, sb + 8192);
    async16(pb, sb + 16384);
    async16(pb + 128 * (long)K, sb + 24576);
    pa += 32;
    pb += 32;
  }
  VMC(8);  // drain tile 0 (4 loads); tiles 1,2 stay in flight
  BAR();
  // own reads for phase (0,0): A(0,tile0) -> A0, B(:,tile0) -> B0
  DSR4(A0, ldsb + aoff0r);
  DSR4(B0, ldsb + boffr);

  // ---- main loop: tiles 0 .. nt-4 (staging tiles 3 .. nt-1) ----
  const int M = nt - 3;
  int tt = 0;
  for (; tt + 2 <= M; tt += 2) {
    PH0(tt, B0, true, VMC(6));
    PH1(tt, B0, B1, true, VMC(6), true);
    PH0(tt + 1, B1, true, VMC(6));
    PH1(tt + 1, B1, B0, true, VMC(6), true);
  }
  if (tt < M) {  // tt == M-1, even tile
    PH0(tt, B0, true, VMC(6));
    PH1(tt, B0, B1, true, VMC(6), true);
  }
  // ---- tail: tiles nt-3 (odd), nt-2 (even), nt-1 (odd); no staging ----
  PH0(nt - 3, B1, false, VMC(4));
  PH1(nt - 3, B1, B0, false, VMC(2), true);
  PH0(nt - 2, B0, false, VMC(0));
  PH1(nt - 2, B0, B1, false, (void)0, true);
  PH0(nt - 1, B1, false, (void)0);
  PH1(nt - 1, B1, B0, false, (void)0, false);

  // ---- epilogue ----
  const int er = (lane >> 4) * 4;
  const int ec = lane & 15;
  if (MODE == 0) {
    // LDS-transposed coalesced store: 2 passes x 128 rows, stride 264 u16.
    u16* Ep = (u16*)lds;
    u16* Cp = (u16*)Cout + z * sC;
    float bv[4];
#pragma unroll
    for (int ni = 0; ni < 4; ++ni)
      bv[ni] = bias ? bias[n0 + wn * 64 + ni * 16 + ec] : 0.0f;
#pragma unroll
    for (int p = 0; p < 2; ++p) {
      __syncthreads();
#pragma unroll
      for (int m2 = 0; m2 < 4; ++m2) {
#pragma unroll
        for (int ni = 0; ni < 4; ++ni) {
#pragma unroll
          for (int i = 0; i < 4; ++i) {
            float val = acc[p * 4 + m2][ni][i] * scale + bv[ni];
            Ep[(wm * 64 + m2 * 16 + er + i) * 264 + wn * 64 + ni * 16 + ec] =
                f2bf(val);
          }
        }
      }
      __syncthreads();
#pragma unroll
      for (int s = 0; s < 8; ++s) {
        int R = w * 2 + (lane >> 5) + s * 16;
        int j = lane & 31;
        uint4 d = *(const uint4*)(Ep + R * 264 + j * 8);
        long gm = m0 + (R >> 6) * 128 + p * 64 + (R & 63);
        *(uint4*)(Cp + gm * (long)N + n0 + j * 8) = d;
      }
    }
  } else {
#pragma unroll
    for (int mi = 0; mi < 8; ++mi) {
#pragma unroll
      for (int ni = 0; ni < 4; ++ni) {
#pragma unroll
        for (int i = 0; i < 4; ++i) {
          long gm = m0 + wm * 128 + mi * 16 + er + i;
          int gc = n0 + wn * 64 + ni * 16 + ec;
          float val = acc[mi][ni][i] * scale;
          if (bias) val += bias[gc];
          if (MODE == 1) {
            long b = gm >> 11, rr = gm & 2047;
            ((u16*)Cout)[b * ((long)N * 2048) + (long)gc * 2048 + rr] = f2bf(val);
          } else {
            ((float*)Cout + z * sC)[gm * (long)N + gc] = val;
          }
        }
      }
    }
  }
}

// ------------------------------------------------------------- softmax ----
__global__ __launch_bounds__(256) void softmax_rows(u16* __restrict__ S, float inv) {
  long row = blockIdx.x;
  u16* p = S + row * 2048;
  int t = threadIdx.x;
  int lane = t & 63, wv = t >> 6;

  uint4 raw = ((const uint4*)p)[t];
  unsigned int wd[4] = {raw.x, raw.y, raw.z, raw.w};
  float v[8];
#pragma unroll
  for (int j = 0; j < 4; ++j) {
    v[2 * j]     = bf2f((u16)(wd[j] & 0xffffu));
    v[2 * j + 1] = bf2f((u16)(wd[j] >> 16));
  }
  float mx = v[0];
#pragma unroll
  for (int j = 1; j < 8; ++j) mx = fmaxf(mx, v[j]);
  for (int off = 32; off; off >>= 1) mx = fmaxf(mx, __shfl_xor(mx, off));
  __shared__ float rmax[4], rsum[4];
  if (lane == 0) rmax[wv] = mx;
  __syncthreads();
  mx = fmaxf(fmaxf(rmax[0], rmax[1]), fmaxf(rmax[2], rmax[3]));

  float e[8], s = 0.f;
#pragma unroll
  for (int j = 0; j < 8; ++j) { e[j] = __expf(v[j] - mx); s += e[j]; }
  for (int off = 32; off; off >>= 1) s += __shfl_xor(s, off);
  if (lane == 0) rsum[wv] = s;
  __syncthreads();
  s = rsum[0] + rsum[1] + rsum[2] + rsum[3];

  float r = inv / s;
  unsigned int o[4];
#pragma unroll
  for (int j = 0; j < 4; ++j)
    o[j] = (unsigned)f2bf(e[2 * j] * r) | ((unsigned)f2bf(e[2 * j + 1] * r) << 16);
  ((uint4*)p)[t] = make_uint4(o[0], o[1], o[2], o[3]);
}

// -------------------------------------------------------------- launch ----
extern "C" void kernel_launch(void* const* d_in, const int* in_sizes, int n_in,
                              void* d_out, int out_size, void* d_ws, size_t ws_size,
                              hipStream_t stream) {
  const float* query = (const float*)d_in[0];
  const float* key_  = (const float*)d_in[1];
  const float* Wq = (const float*)d_in[2];
  const float* bq = (const float*)d_in[3];
  const float* Wk = (const float*)d_in[4];
  const float* bk = (const float*)d_in[5];
  const float* Wv = (const float*)d_in[6];
  const float* bv = (const float*)d_in[7];
  const float* Wo = (const float*)d_in[8];
  const float* bo = (const float*)d_in[9];
  float* out = (float*)d_out;

  const long tokE = 65536L * 512;
  const long bstride = 2048L * 512;

  char* ws = (char*)d_ws;
  u16* Qb = (u16*)(ws);
  u16* Kb = (u16*)(ws + 67108864L);
  u16* vT = (u16*)(ws + 134217728L);
  u16* WT = (u16*)(ws + 201326592L);
  char* Sbase = ws + 203423744L;
  u16* attn = Qb;  // Qb dead after q-projection

  u16* qb = (u16*)d_out;
  u16* kb = (u16*)((char*)d_out + 67108864L);

  long s_avail = (long)ws_size - 203423744L;
  int g = (int)(s_avail / 8388608L);
  if (g < 1) g = 1;
  if (g > 32) g = 32;

  // 1. casts
  cast_f32_to_bf16<<<16384, 256, 0, stream>>>(query, Qb, tokE);
  cast_f32_to_bf16<<<16384, 256, 0, stream>>>(key_, Kb, tokE);
  castWT<<<dim3(1024, 4, 1), 256, 0, stream>>>(Wq, Wk, Wv, Wo, WT);

  // 2. projections (M = 65536 merged)
  dim3 gproj(256, 2, 1);
  gemm256<0><<<gproj, 512, 0, stream>>>(Qb, WT,           bq, qb, 512, 512, 0, 0, 0, 1.0f);
  gemm256<0><<<gproj, 512, 0, stream>>>(Kb, WT + 262144L, bk, kb, 512, 512, 0, 0, 0, 1.0f);
  gemm256<1><<<gproj, 512, 0, stream>>>(Kb, WT + 524288L, bv, vT, 512, 512, 0, 0, 0, 1.0f);

  // 3. attention, grouped by available workspace
  for (int b0 = 0; b0 < 32; b0 += g) {
    int bc = (32 - b0 < g) ? (32 - b0) : g;
    u16* Sg = (u16*)Sbase;
    dim3 gs(8, 8, bc);
    gemm256<0><<<gs, 512, 0, stream>>>(qb + (long)b0 * bstride, kb + (long)b0 * bstride,
                                       nullptr, Sg, 2048, 512,
                                       bstride, bstride, 2048L * 2048, 1.0f / 512.0f);
    softmax_rows<<<bc * 2048, 256, 0, stream>>>(Sg, 1.0f / 2048.0f);
    dim3 gpv(8, 2, bc);
    gemm256<0><<<gpv, 512, 0, stream>>>(Sg, vT + (long)b0 * bstride, nullptr,
                                        attn + (long)b0 * bstride, 512, 2048,
                                        2048L * 2048, bstride, bstride, 1.0f);
  }

  // 4. output projection -> d_out fp32
  gemm256<2><<<dim3(256, 2, 1), 512, 0, stream>>>(attn, WT + 786432L, bo, out,
                                                  512, 512, 0, 0, 0, 1.0f);
}